// Round 9
// baseline (779.336 us; speedup 1.0000x reference)
//
#include <hip/hip_runtime.h>
#include <math.h>

typedef short bf16x8 __attribute__((ext_vector_type(8)));
typedef float f32x4 __attribute__((ext_vector_type(4)));

#define SCALE_Q 0.28867513459481287f  // 1/sqrt(12)

__device__ __forceinline__ ushort f2bf(float f) {
  union { float f; unsigned int i; } v; v.f = f;
  unsigned int x = v.i;
  return (ushort)((x + 0x7fffu + ((x >> 16) & 1u)) >> 16);  // RNE
}
__device__ __forceinline__ float bf2f(ushort u) {
  union { unsigned int i; float f; } v; v.i = ((unsigned int)u) << 16; return v.f;
}
// packed helpers: dword holds 2 bf16 (lo = even tok, hi = odd tok)
__device__ __forceinline__ float bfLo(unsigned int d) {
  union { unsigned int i; float f; } v; v.i = d << 16; return v.f;
}
__device__ __forceinline__ float bfHi(unsigned int d) {
  union { unsigned int i; float f; } v; v.i = d & 0xffff0000u; return v.f;
}
// compiler-only memory fence: orders LDS stores/loads across phase boundaries
// (defeats TBAA-based reordering) with ZERO hardware cost -- within one wave,
// HW LDS ops are in-order, so no s_barrier / waitcnt drain is needed.
#define PHASE_FENCE() asm volatile("" ::: "memory")

// ---------------- pre-kernel: swizzle weights to B-fragment tiles ----------
// (unchanged from round 8 -- passed)
// tile map (108 tiles x 1024 B): [0,54) qkv (Q tiles pre-scaled), [54,72) w1a,
// [72,90) Wfold = merge_w@w1b, [90,108) w2. foldb (96 f32) at byte 110592.
__global__ void swizzle_w(const float* __restrict__ qkv_w,
                          const float* __restrict__ merge_w,
                          const float* __restrict__ merge_b,
                          const float* __restrict__ w1,
                          const float* __restrict__ b1,
                          const float* __restrict__ w2,
                          ushort* __restrict__ ws) {
  int g = blockIdx.x * 256 + threadIdx.x;
  if (g < 6912) {  // 108 tiles * 64 lanes
    int tile = g >> 6, lane = g & 63;
    float vals[8];
    if (tile < 54) {
      int rem = tile % 18;
      int c0 = (tile / 18) * 96 + (rem / 3) * 16, k0 = (rem % 3) * 32;
      int n = c0 + (lane & 15), kb = k0 + (lane >> 4) * 8;
      float s = (tile < 18) ? SCALE_Q : 1.0f;  // fold softmax scale into Q
#pragma unroll
      for (int j = 0; j < 8; ++j) vals[j] = qkv_w[(size_t)(kb + j) * 288 + n] * s;
    } else if (tile < 72) {
      int rem = tile - 54;
      int c0 = (rem / 3) * 16, k0 = (rem % 3) * 32;
      int n = c0 + (lane & 15), kb = k0 + (lane >> 4) * 8;
#pragma unroll
      for (int j = 0; j < 8; ++j) vals[j] = w1[(size_t)(kb + j) * 96 + n];
    } else if (tile < 90) {
      // Wfold[k][n] = sum_m merge_w[k][m] * w1[(96+m)][n]  (fp32)
      int rem = tile - 72;
      int c0 = (rem / 3) * 16, k0 = (rem % 3) * 32;
      int n = c0 + (lane & 15), kb = k0 + (lane >> 4) * 8;
      float acc[8] = {0, 0, 0, 0, 0, 0, 0, 0};
      for (int m = 0; m < 96; ++m) {
        float wr = w1[(size_t)(96 + m) * 96 + n];
#pragma unroll
        for (int j = 0; j < 8; ++j) acc[j] += merge_w[(size_t)(kb + j) * 96 + m] * wr;
      }
#pragma unroll
      for (int j = 0; j < 8; ++j) vals[j] = acc[j];
    } else {
      int rem = tile - 90;
      int c0 = (rem / 3) * 16, k0 = (rem % 3) * 32;
      int n = c0 + (lane & 15), kb = k0 + (lane >> 4) * 8;
#pragma unroll
      for (int j = 0; j < 8; ++j) vals[j] = w2[(size_t)(kb + j) * 96 + n];
    }
    ushort tmp[8];
#pragma unroll
    for (int j = 0; j < 8; ++j) tmp[j] = f2bf(vals[j]);
    *(uint4*)(ws + tile * 512 + lane * 8) = *(const uint4*)tmp;
  } else if (g < 7008) {  // foldb[n] = b1[n] + sum_m merge_b[m]*w1b[m][n]
    int n = g - 6912;
    float s = b1[n];
    for (int m = 0; m < 96; ++m) s += merge_b[m] * w1[(size_t)(96 + m) * 96 + n];
    ((float*)(ws + 55296))[n] = s;
  }
}

// ---------------- main fused kernel: ONE WAVE PER BLOCK, ZERO BARRIERS ------
// block = 64 threads = 1 wave = 16 tokens = 2 windows (a quarter of the old
// 256-thread block). Every phase P1..P7 is wave-private; HW same-wave LDS
// ordering + PHASE_FENCE replace all __syncthreads. LDS arena 11520 B ->
// ~14 independent waves/CU, all free-running (no convoying, no vmcnt drains).
//
// Arena layout (ushorts, total 5760 = 11520 B), regions reused over time:
//   X / msg / (P5 A-src):  [0,1664)        as [tokloc][104]
//   QKV:                   [0,5760)        as [col][QSTR=20]  (over dead X)
//   hmid:                  [1664,3328)     as [tokloc][104]   (over dead Q/K)
//   outR:                  [3840,5760)     as [col][20]       (over dead V)
// Safety: X dead after aX regs read; Q/K/V reads all precede msg writes in
// wave-lockstep program order; V dead after P3; msg dead after P5 aM2 read.
#define XSTR 104
#define QSTR 20
#define HMID 1664
#define OUTR 3840
__global__ __launch_bounds__(64, 4) void swin_mfma(
    const float* __restrict__ x,
    const float* __restrict__ qkv_b, const float* __restrict__ b2,
    const ushort* __restrict__ wsw, float* __restrict__ out) {
  __shared__ __align__(16) ushort R[5760];  // 11520 B

  const int tid = threadIdx.x, bid = blockIdx.x;
  // sibling-locality swizzle: the 4 sub-blocks (wv=0..3) of one old 256-thread
  // block stay within delta-bid <= 24 so their shared 64B x/out lines are
  // L2-hot on the same XCD (bid%8 assumed XCD round-robin; chunked is fine too).
  const int lo3 = bid & 7, wv = (bid >> 3) & 3, hi = bid >> 5;
  const int old = hi * 8 + lo3;
  const int t0 = old & 3, w0 = (old >> 2) & 31, h0 = (old >> 7) & 31, b = old >> 12;
  const int mrow = tid & 15, quad = tid >> 4;
  const int arow = mrow * XSTR + quad * 8;  // A-frag base (block-local rows)
  const int tokb = quad * 4;                // C-frag row base (block-local)
  const float* foldb = (const float*)(wsw + 55296);

  // P1: x -> R[tokloc][XSTR] bf16. Per lane 6 float4 loads (16B granules;
  // siblings share the 64B line via L2). items: (c, dh, dw) = 96*2*2 = 384.
  for (int k = 0; k < 6; ++k) {
    int item = tid + k * 64;
    int c = item >> 2, dh = (item >> 1) & 1, dw = item & 1;
    int base = dh * 4 + dw * 2;
    size_t g = ((((size_t)b * 96 + c) * 64 + h0 * 2 + dh) * 64 + w0 * 2 + dw) * 64 + t0 * 16 + wv * 4;
    float4 v = *(const float4*)(x + g);
    float vv[4] = {v.x, v.y, v.z, v.w};
#pragma unroll
    for (int j = 0; j < 4; ++j) {
      int tokloc = (j >> 1) * 8 + base + (j & 1);
      R[tokloc * XSTR + c] = f2bf(vv[j]);
    }
  }
  PHASE_FENCE();

  bf16x8 aX[3];  // held in registers through P5
#pragma unroll
  for (int kt = 0; kt < 3; ++kt)
    aX[kt] = *(const bf16x8*)(R + arow + kt * 32);
  PHASE_FENCE();  // aX in regs; QKV may now overwrite X

  // P2: QKV (3 chunks of 96 cols) -> R[col*QSTR + tokloc]
  for (int cn = 0; cn < 3; ++cn) {
#pragma unroll
    for (int nt = 0; nt < 6; ++nt) {
      int col = cn * 96 + nt * 16 + mrow;
      float bias = qkv_b[col];
      if (cn == 0) bias *= SCALE_Q;  // Q weights pre-scaled; scale bias too
      f32x4 acc = {bias, bias, bias, bias};
#pragma unroll
      for (int kt = 0; kt < 3; ++kt) {
        bf16x8 bf = *(const bf16x8*)(wsw + (size_t)(cn * 18 + nt * 3 + kt) * 512 + tid * 8);
        acc = __builtin_amdgcn_mfma_f32_16x16x32_bf16(aX[kt], bf, acc, 0, 0, 0);
      }
#pragma unroll
      for (int r = 0; r < 4; ++r) R[col * QSTR + tokb + r] = f2bf(acc[r]);
    }
  }
  PHASE_FENCE();  // QKV visible (same-wave, in-order LDS)

  // P3: attention. thread = (winl, head, 2 query rows); winl in {0,1}.
  // u32 reads only (QSTR=20 is 4B- but not 8B-aligned per column).
  {
    const int winl = tid >> 5, head = (tid >> 2) & 7, r2 = (tid & 3) * 2;
    const ushort* Qb = R + (head * 12) * QSTR + winl * 8;
    const ushort* Kb = R + (96 + head * 12) * QSTR + winl * 8;
    const ushort* Vb = R + (192 + head * 12) * QSTR + winl * 8;
    float q0[12], q1[12];
#pragma unroll
    for (int d = 0; d < 12; ++d) {
      unsigned int qq = *(const unsigned int*)(Qb + d * QSTR + r2);
      q0[d] = bfLo(qq);
      q1[d] = bfHi(qq);
    }
    float s0[8] = {0, 0, 0, 0, 0, 0, 0, 0}, s1[8] = {0, 0, 0, 0, 0, 0, 0, 0};
#pragma unroll
    for (int d = 0; d < 12; ++d) {
      unsigned int ka = *(const unsigned int*)(Kb + d * QSTR);
      unsigned int kb2 = *(const unsigned int*)(Kb + d * QSTR + 2);
      unsigned int kc = *(const unsigned int*)(Kb + d * QSTR + 4);
      unsigned int kd = *(const unsigned int*)(Kb + d * QSTR + 6);
      float kf[8] = {bfLo(ka), bfHi(ka), bfLo(kb2), bfHi(kb2),
                     bfLo(kc), bfHi(kc), bfLo(kd), bfHi(kd)};
#pragma unroll
      for (int m = 0; m < 8; ++m) { s0[m] += q0[d] * kf[m]; s1[m] += q1[d] * kf[m]; }
    }
    float mx0 = fmaxf(fmaxf(fmaxf(s0[0], s0[1]), fmaxf(s0[2], s0[3])),
                      fmaxf(fmaxf(s0[4], s0[5]), fmaxf(s0[6], s0[7])));
    float mx1 = fmaxf(fmaxf(fmaxf(s1[0], s1[1]), fmaxf(s1[2], s1[3])),
                      fmaxf(fmaxf(s1[4], s1[5]), fmaxf(s1[6], s1[7])));
    float sum0 = 0.f, sum1 = 0.f;
#pragma unroll
    for (int m = 0; m < 8; ++m) {
      s0[m] = __expf(s0[m] - mx0); sum0 += s0[m];
      s1[m] = __expf(s1[m] - mx1); sum1 += s1[m];
    }
    float inv0 = 1.0f / sum0, inv1 = 1.0f / sum1;
    float o0[12], o1[12];
#pragma unroll
    for (int d = 0; d < 12; ++d) {
      unsigned int va = *(const unsigned int*)(Vb + d * QSTR);
      unsigned int vb2 = *(const unsigned int*)(Vb + d * QSTR + 2);
      unsigned int vc = *(const unsigned int*)(Vb + d * QSTR + 4);
      unsigned int vd = *(const unsigned int*)(Vb + d * QSTR + 6);
      float vf[8] = {bfLo(va), bfHi(va), bfLo(vb2), bfHi(vb2),
                     bfLo(vc), bfHi(vc), bfLo(vd), bfHi(vd)};
      float a0 = 0.f, a1 = 0.f;
#pragma unroll
      for (int m = 0; m < 8; ++m) { a0 += s0[m] * vf[m]; a1 += s1[m] * vf[m]; }
      o0[d] = a0 * inv0; o1[d] = a1 * inv1;
    }
    // wave-lockstep: every lane's Q/K/V reads precede any lane's msg write
    PHASE_FENCE();
    int tr = winl * 8 + r2;
#pragma unroll
    for (int d = 0; d < 12; ++d) {
      R[tr * XSTR + head * 12 + d] = f2bf(o0[d]);
      R[(tr + 1) * XSTR + head * 12 + d] = f2bf(o1[d]);
    }
  }
  PHASE_FENCE();  // msg visible

  // P5: hmid = gelu(X@w1a + msg@Wfold + foldb) -> R[HMID + tokloc*XSTR + col]
  {
    bf16x8 aM2[3];
#pragma unroll
    for (int kt = 0; kt < 3; ++kt) aM2[kt] = *(const bf16x8*)(R + arow + kt * 32);
#pragma unroll
    for (int nt = 0; nt < 6; ++nt) {
      int col = nt * 16 + mrow;
      float bias = foldb[col];
      f32x4 acc = {bias, bias, bias, bias};
#pragma unroll
      for (int kt = 0; kt < 3; ++kt) {
        bf16x8 bf = *(const bf16x8*)(wsw + (size_t)(54 + nt * 3 + kt) * 512 + tid * 8);
        acc = __builtin_amdgcn_mfma_f32_16x16x32_bf16(aX[kt], bf, acc, 0, 0, 0);
      }
#pragma unroll
      for (int kt = 0; kt < 3; ++kt) {
        bf16x8 bf = *(const bf16x8*)(wsw + (size_t)(72 + nt * 3 + kt) * 512 + tid * 8);
        acc = __builtin_amdgcn_mfma_f32_16x16x32_bf16(aM2[kt], bf, acc, 0, 0, 0);
      }
#pragma unroll
      for (int r = 0; r < 4; ++r) {
        float h = acc[r];
        float gel = 0.5f * h * (1.0f + erff(h * 0.70710678118654752f));
        R[HMID + (tokb + r) * XSTR + col] = f2bf(gel);
      }
    }
  }
  PHASE_FENCE();  // hmid visible

  // P6: out = hmid @ w2 + b2 -> R[OUTR + col*QSTR + tokloc] (over dead V)
  {
    bf16x8 aH[3];
#pragma unroll
    for (int kt = 0; kt < 3; ++kt) aH[kt] = *(const bf16x8*)(R + HMID + arow + kt * 32);
#pragma unroll
    for (int nt = 0; nt < 6; ++nt) {
      int col = nt * 16 + mrow;
      float bias = b2[col];
      f32x4 acc = {bias, bias, bias, bias};
#pragma unroll
      for (int kt = 0; kt < 3; ++kt) {
        bf16x8 bf = *(const bf16x8*)(wsw + (size_t)(90 + nt * 3 + kt) * 512 + tid * 8);
        acc = __builtin_amdgcn_mfma_f32_16x16x32_bf16(aH[kt], bf, acc, 0, 0, 0);
      }
#pragma unroll
      for (int r = 0; r < 4; ++r) R[OUTR + col * QSTR + tokb + r] = f2bf(acc[r]);
    }
  }
  PHASE_FENCE();  // outR visible

  // P7: coalesced float4 store (paired u32 reads: toks base,base+1 / +8)
  for (int k = 0; k < 6; ++k) {
    int item = tid + k * 64;
    int c = item >> 2, dh = (item >> 1) & 1, dw = item & 1;
    int base = dh * 4 + dw * 2;
    unsigned int p0 = *(const unsigned int*)(R + OUTR + c * QSTR + base);
    unsigned int p1 = *(const unsigned int*)(R + OUTR + c * QSTR + 8 + base);
    float4 v = {bfLo(p0), bfHi(p0), bfLo(p1), bfHi(p1)};
    size_t g = ((((size_t)b * 96 + c) * 64 + h0 * 2 + dh) * 64 + w0 * 2 + dw) * 64 + t0 * 16 + wv * 4;
    *(float4*)(out + g) = v;
  }
}

extern "C" void kernel_launch(void* const* d_in, const int* in_sizes, int n_in,
                              void* d_out, int out_size, void* d_ws, size_t ws_size,
                              hipStream_t stream) {
  const float* x = (const float*)d_in[0];
  const float* qkv_w = (const float*)d_in[1];
  const float* qkv_b = (const float*)d_in[2];
  const float* merge_w = (const float*)d_in[3];
  const float* merge_b = (const float*)d_in[4];
  const float* w1 = (const float*)d_in[5];
  const float* b1 = (const float*)d_in[6];
  const float* w2 = (const float*)d_in[7];
  const float* b2 = (const float*)d_in[8];
  ushort* wsw = (ushort*)d_ws;  // needs 110976 B
  swizzle_w<<<dim3(28), dim3(256), 0, stream>>>(qkv_w, merge_w, merge_b, w1, b1, w2, wsw);
  // grid: 4 sub-blocks x (B*h0*w0*t0 = 8192) = 32768 one-wave blocks
  swin_mfma<<<dim3(32768), dim3(64), 0, stream>>>(
      x, qkv_b, b2, wsw, (float*)d_out);
}